// Round 8
// baseline (3417.675 us; speedup 1.0000x reference)
//
#include <hip/hip_runtime.h>
#include <hip/hip_bf16.h>
#include <math.h>

// Problem dims (fixed by the reference)
#define T_  512
#define B_  64
#define I_  512
#define H_  1024
#define HX_ 1536
#define NG  4096          // 4*H packed gate rows
#define RP  17            // reduce-buffer pitch (fp32)
#define NBLK 512          // persistent grid: 2 blocks/CU * 256 CUs (co-resident by construction)

// Barrier layout (v7, kept): COMPACT flags — flag[mh*256 + nt] is ONE dword.
#define BAR_INTS  1024

typedef __attribute__((ext_vector_type(8))) short bf16x8;
typedef __attribute__((ext_vector_type(4))) float floatx4;
typedef unsigned long long ull;

__device__ __forceinline__ float sigmoidf_(float v) { return 1.0f / (1.0f + __expf(-v)); }
__device__ __forceinline__ float tanhf_(float v) {
    float e = __expf(-2.0f * fabsf(v));
    float t = (1.0f - e) / (1.0f + e);
    return copysignf(t, v);
}
__device__ __forceinline__ short f2bf(float f) {
    union { __hip_bfloat16 b; short s; } u;
    u.b = __float2bfloat16(f);   // RNE
    return u.s;
}
__device__ __forceinline__ ull pack4bf(float a, float b, float c, float d) {
    return (ull)(unsigned short)f2bf(a)
         | ((ull)(unsigned short)f2bf(b) << 16)
         | ((ull)(unsigned short)f2bf(c) << 32)
         | ((ull)(unsigned short)f2bf(d) << 48);
}

// ---- prologue: pack Wg -> Wp [4096][HX] bf16, rows r = u*4+g; biases too ----
__global__ __launch_bounds__(256) void pack_w(
    const float* __restrict__ Wf, const float* __restrict__ Wi,
    const float* __restrict__ Wc, const float* __restrict__ Wo,
    const float* __restrict__ bf, const float* __restrict__ bi,
    const float* __restrict__ bc, const float* __restrict__ bo,
    short* __restrict__ Wp, float* __restrict__ bp)
{
    const int r = blockIdx.x;          // 0..4095
    const int u = r >> 2, g = r & 3;
    const float* src; const float* bsrc;
    switch (g) {
        case 0:  src = Wf; bsrc = bf; break;
        case 1:  src = Wi; bsrc = bi; break;
        case 2:  src = Wc; bsrc = bc; break;
        default: src = Wo; bsrc = bo; break;
    }
    src += (size_t)u * HX_;
    for (int off = threadIdx.x; off < HX_; off += 256)
        Wp[(size_t)r * HX_ + off] = f2bf(src[off]);
    if (threadIdx.x == 0) bp[r] = bsrc[u];
}

// ---- persistent-path init: stage bf16(x_t) into hxall[t] x-part for ALL t,
//      zero hxall[0] h-part, zero barrier flags ----
__global__ __launch_bounds__(256) void init_hxall(
    const float* __restrict__ x, short* __restrict__ hxall, unsigned* __restrict__ bar)
{
    const int idx = blockIdx.x * 256 + threadIdx.x;
    const int nx4 = T_ * B_ * I_ / 4;               // 4,194,304 quads
    if (idx < nx4) {
        const int e = idx * 4;                      // element index into x
        const int t = e >> 15;                      // / (B_*I_)
        const int r = e & (B_ * I_ - 1);
        const int b = r >> 9, p = r & 511;
        const float4 xv = *(const float4*)(x + (size_t)e);
        *(ull*)(hxall + (size_t)t * (B_ * HX_) + (size_t)b * HX_ + H_ + p)
            = pack4bf(xv.x, xv.y, xv.z, xv.w);
    } else if (idx < nx4 + B_ * H_ / 4) {           // zero slot-0 h-part
        const int k = (idx - nx4) * 4;
        const int b = k >> 10, p = k & 1023;
        *(ull*)(hxall + (size_t)b * HX_ + p) = 0ull;
    }
    if (idx < BAR_INTS) bar[idx] = 0u;
}

// ---- persistent LSTM: all 512 timesteps in one PLAIN-launched kernel ----
// Base = verified v7 (3279 us). v8 changes:
//  (1) out staged block-contiguously in outw[bid][t][tid] (512B full lines,
//      no cross-XCD false sharing, no write-allocate HBM fetch) and stored
//      AFTER the arrive flag -> drains under the barrier wait, off the
//      critical pre-flag vmcnt(0) drain. Final reorder kernel produces
//      [T][B][H]. If outw==nullptr (ws too small) falls back to v7 direct
//      stores (also moved post-flag).
//  (2) h-phase prefetch deepened to all-8 loads before the first MFMA
//      (one exposed L3 latency instead of two).
__global__ __launch_bounds__(512, 4) void lstm_all(
    const short* __restrict__ Wp, const float* __restrict__ bp,
    short* __restrict__ hxall,            // [T_+1][B_][HX_] bf16
    unsigned* __restrict__ bar,
    float* __restrict__ out,              // [T_][B_][H_]
    float* __restrict__ outw)             // [NBLK][T_][128] or nullptr
{
    __shared__ __align__(16) float red[4 * 32 * RP];

    const int tid  = threadIdx.x;
    const int bid  = blockIdx.x;          // 0..511
    const int nt   = bid & 255;
    const int mh   = bid >> 8;
    const int lane = tid & 63;
    const int wv   = tid >> 6;            // 0..7
    const int w    = wv & 1;
    const int kq   = wv >> 1;
    const int n16  = lane & 15;
    const int quad = lane >> 4;
    const int n0   = nt * 16;
    const int j0   = nt * 4;
    const int mrow = mh * 32 + w * 16 + n16;

    // Weights: load once, pinned for all 512 steps. 8 h-frags + 4 x-frags.
    bf16x8 bfh[8], bfx[4];
    {
        const short* brow = Wp + (size_t)(n0 + n16) * HX_ + quad * 8;
        #pragma unroll
        for (int f = 0; f < 8; ++f) bfh[f] = *(const bf16x8*)(brow + kq * 256 + f * 32);
        #pragma unroll
        for (int f = 0; f < 4; ++f) bfx[f] = *(const bf16x8*)(brow + 1024 + kq * 128 + f * 32);
    }

    // Epilogue-role constants (tid < 128): thread = (batch b_loc, unit j0+u)
    const int b_loc = tid >> 2;
    const int u     = tid & 3;
    const int gb    = mh * 32 + b_loc;
    const float4 bias = *(const float4*)(bp + n0 + u * 4);
    float c = 0.0f;

    // Running pointers (advance by one time-slot per step)
    const short* sp = hxall + (size_t)mrow * HX_ + quad * 8;                // A row base, slot t
    ull* hd = (ull*)(hxall + (size_t)(B_ * HX_) + (size_t)gb * HX_ + j0);   // h dst (slot t+1)
    float* op = out + (size_t)gb * H_ + j0 + u;                             // direct-out fallback
    float* ow = outw ? (outw + (size_t)bid * T_ * 128 + tid) : nullptr;     // staged out

    unsigned* const flagp = bar + (unsigned)(mh * 256 + nt);                // own dword
    const unsigned* const pollp = bar + (unsigned)(mh * 256 + lane * 4);    // 4 dwords/lane

    // x-phase for t=0 (x-part of A is init-staged for all t)
    floatx4 acc = {0.f, 0.f, 0.f, 0.f};
    {
        const short* ax = sp + 1024 + kq * 128;
        bf16x8 xa[4];
        #pragma unroll
        for (int f = 0; f < 4; ++f) xa[f] = *(const bf16x8*)(ax + f * 32);
        #pragma unroll
        for (int f = 0; f < 4; ++f)
            acc = __builtin_amdgcn_mfma_f32_16x16x32_bf16(xa[f], bfx[f], acc, 0, 0, 0);
    }

    for (int t = 0; t < T_; ++t) {
        // h-phase: all 8 A-frag loads issued, then 8 MFMAs (one exposed latency)
        {
            const short* ah = sp + kq * 256;
            bf16x8 ha[8];
            #pragma unroll
            for (int i = 0; i < 8; ++i) ha[i] = *(const bf16x8*)(ah + i * 32);
            #pragma unroll
            for (int kf = 0; kf < 8; ++kf)
                acc = __builtin_amdgcn_mfma_f32_16x16x32_bf16(ha[kf], bfh[kf], acc, 0, 0, 0);
        }

        // C/D layout: col = lane&15, row = quad*4 + reg
        #pragma unroll
        for (int i2 = 0; i2 < 4; ++i2)
            red[(kq * 32 + w * 16 + quad * 4 + i2) * RP + n16] = acc[i2];
        __syncthreads();

        float h = 0.0f;
        if (tid < 128) {
            float gv[4];
            #pragma unroll
            for (int gg = 0; gg < 4; ++gg) {
                const int col = u * 4 + gg;
                gv[gg] = red[(0 * 32 + b_loc) * RP + col]
                       + red[(1 * 32 + b_loc) * RP + col]
                       + red[(2 * 32 + b_loc) * RP + col]
                       + red[(3 * 32 + b_loc) * RP + col];
            }
            const float F  = sigmoidf_(gv[0] + bias.x);
            const float In = sigmoidf_(gv[1] + bias.y);
            const float G  = tanhf_(gv[2] + bias.z);
            const float O  = sigmoidf_(gv[3] + bias.w);
            c = F * c + In * G;
            h = O * tanhf_(c);
            // gather the 4 units of this (batch, j0-block) into one 8B
            // device-coherent store (lanes u=0..3 are adjacent)
            const int hv = (int)(unsigned short)f2bf(h);
            const int base = lane & ~3;
            const int a0 = __shfl(hv, base + 0);
            const int a1 = __shfl(hv, base + 1);
            const int a2 = __shfl(hv, base + 2);
            const int a3 = __shfl(hv, base + 3);
            if (u == 0) {
                const ull pk = (ull)(unsigned)(unsigned short)a0
                             | ((ull)(unsigned)(unsigned short)a1 << 16)
                             | ((ull)(unsigned)(unsigned short)a2 << 32)
                             | ((ull)(unsigned)(unsigned short)a3 << 48);
                __hip_atomic_store(hd, pk, __ATOMIC_RELAXED, __HIP_MEMORY_SCOPE_AGENT);
            }
        }
        // Drain h stores (s_waitcnt vmcnt(0) before s_barrier), THEN arrive:
        // h is durable at the coherence point before the flag becomes visible.
        // NOTE: out/outw stores are issued AFTER this point -> off this drain.
        __syncthreads();

        if (t + 1 < T_) {
            const unsigned tgt = (unsigned)(t + 1);
            if (tid == 0)
                __hip_atomic_store(flagp, tgt, __ATOMIC_RELAXED,
                                   __HIP_MEMORY_SCOPE_AGENT);

            // out store — off the critical path, drains under the barrier wait
            if (tid < 128) {
                if (ow) ow[0] = h; else *op = h;
            }

            // x-phase for t+1 — overlapped with the barrier wait
            acc = floatx4{0.f, 0.f, 0.f, 0.f};
            {
                const short* ax = sp + (B_ * HX_) + 1024 + kq * 128;
                bf16x8 xa[4];
                #pragma unroll
                for (int f = 0; f < 4; ++f) xa[f] = *(const bf16x8*)(ax + f * 32);
                #pragma unroll
                for (int f = 0; f < 4; ++f)
                    acc = __builtin_amdgcn_mfma_f32_16x16x32_bf16(xa[f], bfx[f], acc, 0, 0, 0);
            }

            // FLAT one-hop barrier over compact flags: wave0 scans the
            // group's 256 dwords (8 cache lines), 4 contiguous dwords/lane.
            if (tid < 64) {
                for (unsigned it = 0; it < 4096u; ++it) {
                    const unsigned v0 = __hip_atomic_load(pollp + 0, __ATOMIC_RELAXED, __HIP_MEMORY_SCOPE_AGENT);
                    const unsigned v1 = __hip_atomic_load(pollp + 1, __ATOMIC_RELAXED, __HIP_MEMORY_SCOPE_AGENT);
                    const unsigned v2 = __hip_atomic_load(pollp + 2, __ATOMIC_RELAXED, __HIP_MEMORY_SCOPE_AGENT);
                    const unsigned v3 = __hip_atomic_load(pollp + 3, __ATOMIC_RELAXED, __HIP_MEMORY_SCOPE_AGENT);
                    const int ok = (v0 >= tgt) && (v1 >= tgt) && (v2 >= tgt) && (v3 >= tgt);
                    if (__all(ok)) break;
                    __builtin_amdgcn_s_sleep(2);
                }
            }
            __syncthreads();
        } else {
            // last step: just emit the out values
            if (tid < 128) {
                if (ow) ow[0] = h; else *op = h;
            }
        }

        sp += B_ * HX_;
        hd += (B_ * HX_) / 4;     // ull increments
        op += B_ * H_;
        if (ow) ow += 128;
    }
}

// ---- scatter outw [bid][t][128] -> out [T][B][H] (one block per t) ----
__global__ __launch_bounds__(512) void reorder_out(
    const float* __restrict__ outw, float* __restrict__ out)
{
    const int t = blockIdx.x;
    float* dst = out + (size_t)t * (B_ * H_);
    for (int idx = threadIdx.x; idx < B_ * H_; idx += 512) {
        const int b  = idx >> 10;          // /H_
        const int j  = idx & 1023;
        const int nt = j >> 2, u = j & 3;
        const int mh = b >> 5, bl = b & 31;
        dst[idx] = outw[((size_t)(mh * 256 + nt) * T_ + t) * 128 + bl * 4 + u];
    }
}

// ================= fallback path (proven multi-launch kernels) =================

__global__ __launch_bounds__(256) void init_all(
    const float* __restrict__ x0, short* __restrict__ hx0, float* __restrict__ cws)
{
    int idx = blockIdx.x * 256 + threadIdx.x;
    if (idx < B_ * HX_) {
        int b = idx / HX_, p = idx % HX_;
        hx0[idx] = (p < H_) ? (short)0 : f2bf(x0[b * I_ + (p - H_)]);
    } else if (idx < B_ * HX_ + 512 * 128) {
        cws[idx - B_ * HX_] = 0.0f;
    }
}

__global__ __launch_bounds__(512, 4) void lstm_step(
    const short* __restrict__ Wp, const float* __restrict__ bp,
    const short* __restrict__ hxsrc, short* __restrict__ hxdst,
    const float* __restrict__ xnext, float* __restrict__ cws,
    float* __restrict__ out_t)
{
    __shared__ __align__(16) float red[4 * 32 * RP];

    const int tid  = threadIdx.x;
    const int nt   = blockIdx.x;
    const int mh   = blockIdx.y;
    const int lane = tid & 63;
    const int wv   = tid >> 6;
    const int w    = wv & 1;
    const int kq   = wv >> 1;
    const int n16  = lane & 15;
    const int quad = lane >> 4;
    const int n0   = nt * 16;
    const int j0   = nt * 4;
    const int mrow = mh * 32 + w * 16 + n16;

    const short* __restrict__ arow = hxsrc + mrow * HX_ + kq * 384 + quad * 8;
    const short* __restrict__ brow = Wp + (size_t)(n0 + n16) * HX_ + kq * 384 + quad * 8;

    bf16x8 bfr[12];
    #pragma unroll
    for (int i = 0; i < 12; ++i) bfr[i] = *(const bf16x8*)(brow + i * 32);
    bf16x8 afr[4];
    #pragma unroll
    for (int i = 0; i < 4; ++i) afr[i] = *(const bf16x8*)(arow + i * 32);

    floatx4 acc = {0.f, 0.f, 0.f, 0.f};
    #pragma unroll
    for (int kf = 0; kf < 12; ++kf) {
        acc = __builtin_amdgcn_mfma_f32_16x16x32_bf16(afr[kf & 3], bfr[kf], acc, 0, 0, 0);
        if (kf + 4 < 12) afr[kf & 3] = *(const bf16x8*)(arow + (kf + 4) * 32);
    }

    #pragma unroll
    for (int i2 = 0; i2 < 4; ++i2)
        red[(kq * 32 + w * 16 + quad * 4 + i2) * RP + n16] = acc[i2];
    __syncthreads();

    if (tid < 128) {
        const int b_loc = tid >> 2, u = tid & 3;
        float4 bias = *(const float4*)(bp + n0 + u * 4);
        float gv[4];
        #pragma unroll
        for (int gg = 0; gg < 4; ++gg) {
            const int col = u * 4 + gg;
            float s = red[(0 * 32 + b_loc) * RP + col]
                    + red[(1 * 32 + b_loc) * RP + col]
                    + red[(2 * 32 + b_loc) * RP + col]
                    + red[(3 * 32 + b_loc) * RP + col];
            gv[gg] = s;
        }
        float F  = sigmoidf_(gv[0] + bias.x);
        float In = sigmoidf_(gv[1] + bias.y);
        float G  = tanhf_(gv[2] + bias.z);
        float O  = sigmoidf_(gv[3] + bias.w);
        const int cidx = (mh * 256 + nt) * 128 + tid;
        float c = cws[cidx];
        c = F * c + In * G;
        cws[cidx] = c;
        float h = O * tanhf_(c);
        const int gb = mh * 32 + b_loc;
        out_t[(size_t)gb * H_ + j0 + u] = h;
        hxdst[gb * HX_ + j0 + u] = f2bf(h);
    } else if (tid < 192) {
        if (xnext) {
            const int e = (mh * 256 + nt) * 64 + (tid - 128);
            const int b = e >> 9, p = e & 511;
            hxdst[b * HX_ + H_ + p] = f2bf(xnext[e]);
        }
    }
}

// ================================ launcher ================================

extern "C" void kernel_launch(void* const* d_in, const int* in_sizes, int n_in,
                              void* d_out, int out_size, void* d_ws, size_t ws_size,
                              hipStream_t stream) {
    const float* x  = (const float*)d_in[0];
    const float* Wf = (const float*)d_in[1];
    const float* bf = (const float*)d_in[2];
    const float* Wi = (const float*)d_in[3];
    const float* bi = (const float*)d_in[4];
    const float* Wc = (const float*)d_in[5];
    const float* bc = (const float*)d_in[6];
    const float* Wo = (const float*)d_in[7];
    const float* bo = (const float*)d_in[8];
    float* out = (float*)d_out;

    // ws layout (bytes):
    //   Wp    : 4096*1536*2      = 12,582,912
    //   bp    : 4096*4           =     16,384
    //   bar   : 1024*4           =      4,096
    //   hx0/1 : 2*64*1536*2      =    393,216   (fallback)
    //   cws   : 512*128*4        =    262,144   (fallback)
    //   hxall : 513*64*1536*2    = 100,859,904  (persistent)  -> "need" ~114.1 MB
    //   outw  : 512*512*128*4    = 134,217,728  (optional)    -> "need_big" ~248 MB
    char* wsb = (char*)d_ws;
    size_t off = 0;
    short*    Wp    = (short*)(wsb + off);    off += (size_t)NG * HX_ * 2;
    float*    bp    = (float*)(wsb + off);    off += (size_t)NG * 4;
    unsigned* bar   = (unsigned*)(wsb + off); off += (size_t)BAR_INTS * 4;
    short*    hx0   = (short*)(wsb + off);    off += (size_t)B_ * HX_ * 2;
    short*    hx1   = (short*)(wsb + off);    off += (size_t)B_ * HX_ * 2;
    float*    cws   = (float*)(wsb + off);    off += (size_t)512 * 128 * 4;
    short*    hxall = (short*)(wsb + off);    off += (size_t)(T_ + 1) * B_ * HX_ * 2;
    const size_t need = off;
    float*    outw  = (float*)(wsb + off);
    const size_t need_big = off + (size_t)NBLK * T_ * 128 * 4;

    pack_w<<<NG, 256, 0, stream>>>(Wf, Wi, Wc, Wo, bf, bi, bc, bo, Wp, bp);

    if (ws_size >= need) {
        const int nx4 = T_ * B_ * I_ / 4;
        init_hxall<<<(nx4 + B_ * H_ / 4 + 255) / 256, 256, 0, stream>>>(x, hxall, bar);
        float* outw_arg = (ws_size >= need_big) ? outw : nullptr;
        lstm_all<<<dim3(NBLK), dim3(512), 0, stream>>>(Wp, bp, hxall, bar, out, outw_arg);
        if (outw_arg)
            reorder_out<<<T_, 512, 0, stream>>>(outw, out);
        return;
    }

    init_all<<<(B_ * HX_ + 512 * 128 + 255) / 256, 256, 0, stream>>>(x, hx0, cws);
    for (int t = 0; t < T_; ++t) {
        const short* hxsrc = (t & 1) ? hx1 : hx0;
        short*       hxdst = (t & 1) ? hx0 : hx1;
        const float* xnext = (t + 1 < T_) ? (x + (size_t)(t + 1) * B_ * I_) : nullptr;
        lstm_step<<<dim3(256, 2), 512, 0, stream>>>(
            Wp, bp, hxsrc, hxdst, xnext, cws,
            out + (size_t)t * B_ * H_);
    }
}

// Round 9
// 2174.472 us; speedup vs baseline: 1.5717x; 1.5717x over previous
//
#include <hip/hip_runtime.h>
#include <hip/hip_bf16.h>
#include <math.h>

// Problem dims (fixed by the reference)
#define T_  512
#define B_  64
#define I_  512
#define H_  1024
#define HX_ 1536
#define NG  4096          // 4*H packed gate rows
#define RP  17            // fallback reduce-buffer pitch (fp32)
#define RP2 33            // v9 reduce-buffer pitch: [kq][32 rows][32 cols]
#define NBLK 256          // v9 grid: 1 block/CU -> co-resident by construction

// Barrier (v7 pattern, half size): flag[mh*128 + nt] is ONE dword.
// Each 128-flag group = 512B = 4 cache lines. Plain 4B agent stores, no RMW.
#define BAR_INTS  1024    // 4KB buffer (only 256 used)

typedef __attribute__((ext_vector_type(8))) short bf16x8;
typedef __attribute__((ext_vector_type(4))) float floatx4;
typedef unsigned long long ull;

__device__ __forceinline__ float sigmoidf_(float v) { return 1.0f / (1.0f + __expf(-v)); }
__device__ __forceinline__ float tanhf_(float v) {
    float e = __expf(-2.0f * fabsf(v));
    float t = (1.0f - e) / (1.0f + e);
    return copysignf(t, v);
}
__device__ __forceinline__ short f2bf(float f) {
    union { __hip_bfloat16 b; short s; } u;
    u.b = __float2bfloat16(f);   // RNE
    return u.s;
}
__device__ __forceinline__ ull pack4bf(float a, float b, float c, float d) {
    return (ull)(unsigned short)f2bf(a)
         | ((ull)(unsigned short)f2bf(b) << 16)
         | ((ull)(unsigned short)f2bf(c) << 32)
         | ((ull)(unsigned short)f2bf(d) << 48);
}

// ---- prologue: pack Wg -> Wp [4096][HX] bf16, rows r = u*4+g; biases too ----
__global__ __launch_bounds__(256) void pack_w(
    const float* __restrict__ Wf, const float* __restrict__ Wi,
    const float* __restrict__ Wc, const float* __restrict__ Wo,
    const float* __restrict__ bf, const float* __restrict__ bi,
    const float* __restrict__ bc, const float* __restrict__ bo,
    short* __restrict__ Wp, float* __restrict__ bp)
{
    const int r = blockIdx.x;          // 0..4095
    const int u = r >> 2, g = r & 3;
    const float* src; const float* bsrc;
    switch (g) {
        case 0:  src = Wf; bsrc = bf; break;
        case 1:  src = Wi; bsrc = bi; break;
        case 2:  src = Wc; bsrc = bc; break;
        default: src = Wo; bsrc = bo; break;
    }
    src += (size_t)u * HX_;
    for (int off = threadIdx.x; off < HX_; off += 256)
        Wp[(size_t)r * HX_ + off] = f2bf(src[off]);
    if (threadIdx.x == 0) bp[r] = bsrc[u];
}

// ---- persistent-path init: stage bf16(x_t) into hxall[t] x-part for ALL t,
//      zero hxall[0] h-part, zero barrier flags ----
__global__ __launch_bounds__(256) void init_hxall(
    const float* __restrict__ x, short* __restrict__ hxall, unsigned* __restrict__ bar)
{
    const int idx = blockIdx.x * 256 + threadIdx.x;
    const int nx4 = T_ * B_ * I_ / 4;               // 4,194,304 quads
    if (idx < nx4) {
        const int e = idx * 4;                      // element index into x
        const int t = e >> 15;                      // / (B_*I_)
        const int r = e & (B_ * I_ - 1);
        const int b = r >> 9, p = r & 511;
        const float4 xv = *(const float4*)(x + (size_t)e);
        *(ull*)(hxall + (size_t)t * (B_ * HX_) + (size_t)b * HX_ + H_ + p)
            = pack4bf(xv.x, xv.y, xv.z, xv.w);
    } else if (idx < nx4 + B_ * H_ / 4) {           // zero slot-0 h-part
        const int k = (idx - nx4) * 4;
        const int b = k >> 10, p = k & 1023;
        *(ull*)(hxall + (size_t)b * HX_ + p) = 0ull;
    }
    if (idx < BAR_INTS) bar[idx] = 0u;
}

// ---- persistent LSTM v9: 256 blocks x 512 thr, 1 block/CU ----
// Derived from the verified v7 (3279 us). Change: each block covers N=32
// gate-cols (two 16-col tiles sharing ONE set of A-fragments) -> grid and
// barrier participants halve (2 groups x 128), total L2 A-traffic halves
// (24 MB/step), straggler population halves, no CU sharing. Barrier pattern
// (compact flags, plain agent stores, s_sleep(2) poll, 4096-round watchdog)
// and K-split/x-phase-overlap identical to v7. Out stored directly post-flag
// (v8 showed the out drain is off the critical path; reorder dropped).
__global__ __launch_bounds__(512, 2) void lstm_all(
    const short* __restrict__ Wp, const float* __restrict__ bp,
    short* __restrict__ hxall,            // [T_+1][B_][HX_] bf16
    unsigned* __restrict__ bar,
    float* __restrict__ out)              // [T_][B_][H_]
{
    __shared__ __align__(16) float red[4 * 32 * RP2];

    const int tid  = threadIdx.x;
    const int bid  = blockIdx.x;          // 0..255
    const int nt   = bid & 127;           // 32-gate-col group
    const int mh   = bid >> 7;            // batch half
    const int lane = tid & 63;
    const int wv   = tid >> 6;            // 0..7
    const int w    = wv & 1;              // M 16-row half
    const int kq   = wv >> 1;             // K quarter
    const int n16  = lane & 15;
    const int quad = lane >> 4;
    const int n0   = nt * 32;             // packed gate-col base (32 cols)
    const int j0   = nt * 8;              // hidden-unit base (8 units)
    const int mrow = mh * 32 + w * 16 + n16;

    // Weights: pinned for all 512 steps. Two N-tiles: 2x(8 h + 4 x) frags.
    bf16x8 bfh0[8], bfh1[8], bfx0[4], bfx1[4];
    {
        const short* br0 = Wp + (size_t)(n0 + n16) * HX_ + quad * 8;
        const short* br1 = Wp + (size_t)(n0 + 16 + n16) * HX_ + quad * 8;
        #pragma unroll
        for (int f = 0; f < 8; ++f) {
            bfh0[f] = *(const bf16x8*)(br0 + kq * 256 + f * 32);
            bfh1[f] = *(const bf16x8*)(br1 + kq * 256 + f * 32);
        }
        #pragma unroll
        for (int f = 0; f < 4; ++f) {
            bfx0[f] = *(const bf16x8*)(br0 + 1024 + kq * 128 + f * 32);
            bfx1[f] = *(const bf16x8*)(br1 + 1024 + kq * 128 + f * 32);
        }
    }

    // Epilogue-role constants (tid < 256): thread = (row b_loc, unit j0+uu)
    const int b_loc = tid >> 3;           // 0..31
    const int uu    = tid & 7;            // 0..7
    const int gb    = mh * 32 + b_loc;
    const float4 bias = *(const float4*)(bp + n0 + uu * 4);
    float c = 0.0f;

    // Running pointers (advance one time-slot per step)
    const short* sp = hxall + (size_t)mrow * HX_ + quad * 8;                 // A row base, slot t
    ull* hd = (ull*)(hxall + (size_t)(B_ * HX_) + (size_t)gb * HX_ + j0 + (uu & 4)); // h dst slot t+1
    float* op = out + (size_t)gb * H_ + j0 + uu;

    unsigned* const flagp = bar + (unsigned)(mh * 128 + nt);                 // own dword
    const unsigned* const pollp = bar + (unsigned)(mh * 128 + lane * 2);     // 2 dwords/lane

    // x-phase for t=0 (x-part of A is init-staged for all t)
    floatx4 acc0 = {0.f, 0.f, 0.f, 0.f}, acc1 = {0.f, 0.f, 0.f, 0.f};
    {
        const short* ax = sp + 1024 + kq * 128;
        bf16x8 xa[4];
        #pragma unroll
        for (int f = 0; f < 4; ++f) xa[f] = *(const bf16x8*)(ax + f * 32);
        #pragma unroll
        for (int f = 0; f < 4; ++f) {
            acc0 = __builtin_amdgcn_mfma_f32_16x16x32_bf16(xa[f], bfx0[f], acc0, 0, 0, 0);
            acc1 = __builtin_amdgcn_mfma_f32_16x16x32_bf16(xa[f], bfx1[f], acc1, 0, 0, 0);
        }
    }

    for (int t = 0; t < T_; ++t) {
        // h-phase: 8 shared A-frag loads feed BOTH N-tiles (16 MFMAs)
        {
            const short* ah = sp + kq * 256;
            bf16x8 ha[8];
            #pragma unroll
            for (int i = 0; i < 8; ++i) ha[i] = *(const bf16x8*)(ah + i * 32);
            #pragma unroll
            for (int kf = 0; kf < 8; ++kf) {
                acc0 = __builtin_amdgcn_mfma_f32_16x16x32_bf16(ha[kf], bfh0[kf], acc0, 0, 0, 0);
                acc1 = __builtin_amdgcn_mfma_f32_16x16x32_bf16(ha[kf], bfh1[kf], acc1, 0, 0, 0);
            }
        }

        // C/D layout: batch row = quad*4 + reg (within w-half), gate col = n16
        #pragma unroll
        for (int i2 = 0; i2 < 4; ++i2) {
            const int rr = (kq * 32 + w * 16 + quad * 4 + i2) * RP2;
            red[rr + n16]      = acc0[i2];
            red[rr + 16 + n16] = acc1[i2];
        }
        __syncthreads();

        float h = 0.0f;
        if (tid < 256) {
            float gv[4];
            #pragma unroll
            for (int gg = 0; gg < 4; ++gg) {
                const int col = uu * 4 + gg;
                gv[gg] = red[(0 * 32 + b_loc) * RP2 + col]
                       + red[(1 * 32 + b_loc) * RP2 + col]
                       + red[(2 * 32 + b_loc) * RP2 + col]
                       + red[(3 * 32 + b_loc) * RP2 + col];
            }
            const float F  = sigmoidf_(gv[0] + bias.x);
            const float In = sigmoidf_(gv[1] + bias.y);
            const float G  = tanhf_(gv[2] + bias.z);
            const float O  = sigmoidf_(gv[3] + bias.w);
            c = F * c + In * G;
            h = O * tanhf_(c);
            // pack 4 adjacent units (same b_loc) into one 8B agent store
            const int hv = (int)(unsigned short)f2bf(h);
            const int base = lane & ~3;
            const int a0 = __shfl(hv, base + 0);
            const int a1 = __shfl(hv, base + 1);
            const int a2 = __shfl(hv, base + 2);
            const int a3 = __shfl(hv, base + 3);
            if ((uu & 3) == 0) {
                const ull pk = (ull)(unsigned)(unsigned short)a0
                             | ((ull)(unsigned)(unsigned short)a1 << 16)
                             | ((ull)(unsigned)(unsigned short)a2 << 32)
                             | ((ull)(unsigned)(unsigned short)a3 << 48);
                __hip_atomic_store(hd, pk, __ATOMIC_RELAXED, __HIP_MEMORY_SCOPE_AGENT);
            }
        }
        // Drain h stores (s_waitcnt vmcnt(0) before s_barrier), THEN arrive.
        __syncthreads();

        if (t + 1 < T_) {
            const unsigned tgt = (unsigned)(t + 1);
            if (tid == 0)
                __hip_atomic_store(flagp, tgt, __ATOMIC_RELAXED,
                                   __HIP_MEMORY_SCOPE_AGENT);

            // out store — off the critical path, drains under the barrier wait
            if (tid < 256) *op = h;

            // x-phase for t+1 — overlapped with the barrier wait
            acc0 = floatx4{0.f, 0.f, 0.f, 0.f};
            acc1 = floatx4{0.f, 0.f, 0.f, 0.f};
            {
                const short* ax = sp + (B_ * HX_) + 1024 + kq * 128;
                bf16x8 xa[4];
                #pragma unroll
                for (int f = 0; f < 4; ++f) xa[f] = *(const bf16x8*)(ax + f * 32);
                #pragma unroll
                for (int f = 0; f < 4; ++f) {
                    acc0 = __builtin_amdgcn_mfma_f32_16x16x32_bf16(xa[f], bfx0[f], acc0, 0, 0, 0);
                    acc1 = __builtin_amdgcn_mfma_f32_16x16x32_bf16(xa[f], bfx1[f], acc1, 0, 0, 0);
                }
            }

            // FLAT one-hop barrier: wave0 scans the group's 128 flag dwords
            // (4 cache lines), 2 contiguous dwords/lane.
            if (tid < 64) {
                for (unsigned it = 0; it < 4096u; ++it) {
                    const unsigned v0 = __hip_atomic_load(pollp + 0, __ATOMIC_RELAXED, __HIP_MEMORY_SCOPE_AGENT);
                    const unsigned v1 = __hip_atomic_load(pollp + 1, __ATOMIC_RELAXED, __HIP_MEMORY_SCOPE_AGENT);
                    const int ok = (v0 >= tgt) && (v1 >= tgt);
                    if (__all(ok)) break;
                    __builtin_amdgcn_s_sleep(2);
                }
            }
            __syncthreads();
        } else {
            if (tid < 256) *op = h;     // last step: emit out
        }

        sp += B_ * HX_;
        hd += (B_ * HX_) / 4;     // ull increments
        op += B_ * H_;
    }
}

// ================= fallback path (proven multi-launch kernels) =================

__global__ __launch_bounds__(256) void init_all(
    const float* __restrict__ x0, short* __restrict__ hx0, float* __restrict__ cws)
{
    int idx = blockIdx.x * 256 + threadIdx.x;
    if (idx < B_ * HX_) {
        int b = idx / HX_, p = idx % HX_;
        hx0[idx] = (p < H_) ? (short)0 : f2bf(x0[b * I_ + (p - H_)]);
    } else if (idx < B_ * HX_ + 512 * 128) {
        cws[idx - B_ * HX_] = 0.0f;
    }
}

__global__ __launch_bounds__(512, 4) void lstm_step(
    const short* __restrict__ Wp, const float* __restrict__ bp,
    const short* __restrict__ hxsrc, short* __restrict__ hxdst,
    const float* __restrict__ xnext, float* __restrict__ cws,
    float* __restrict__ out_t)
{
    __shared__ __align__(16) float red[4 * 32 * RP];

    const int tid  = threadIdx.x;
    const int nt   = blockIdx.x;
    const int mh   = blockIdx.y;
    const int lane = tid & 63;
    const int wv   = tid >> 6;
    const int w    = wv & 1;
    const int kq   = wv >> 1;
    const int n16  = lane & 15;
    const int quad = lane >> 4;
    const int n0   = nt * 16;
    const int j0   = nt * 4;
    const int mrow = mh * 32 + w * 16 + n16;

    const short* __restrict__ arow = hxsrc + mrow * HX_ + kq * 384 + quad * 8;
    const short* __restrict__ brow = Wp + (size_t)(n0 + n16) * HX_ + kq * 384 + quad * 8;

    bf16x8 bfr[12];
    #pragma unroll
    for (int i = 0; i < 12; ++i) bfr[i] = *(const bf16x8*)(brow + i * 32);
    bf16x8 afr[4];
    #pragma unroll
    for (int i = 0; i < 4; ++i) afr[i] = *(const bf16x8*)(arow + i * 32);

    floatx4 acc = {0.f, 0.f, 0.f, 0.f};
    #pragma unroll
    for (int kf = 0; kf < 12; ++kf) {
        acc = __builtin_amdgcn_mfma_f32_16x16x32_bf16(afr[kf & 3], bfr[kf], acc, 0, 0, 0);
        if (kf + 4 < 12) afr[kf & 3] = *(const bf16x8*)(arow + (kf + 4) * 32);
    }

    #pragma unroll
    for (int i2 = 0; i2 < 4; ++i2)
        red[(kq * 32 + w * 16 + quad * 4 + i2) * RP + n16] = acc[i2];
    __syncthreads();

    if (tid < 128) {
        const int b_loc = tid >> 2, u = tid & 3;
        float4 bias = *(const float4*)(bp + n0 + u * 4);
        float gv[4];
        #pragma unroll
        for (int gg = 0; gg < 4; ++gg) {
            const int col = u * 4 + gg;
            float s = red[(0 * 32 + b_loc) * RP + col]
                    + red[(1 * 32 + b_loc) * RP + col]
                    + red[(2 * 32 + b_loc) * RP + col]
                    + red[(3 * 32 + b_loc) * RP + col];
            gv[gg] = s;
        }
        float F  = sigmoidf_(gv[0] + bias.x);
        float In = sigmoidf_(gv[1] + bias.y);
        float G  = tanhf_(gv[2] + bias.z);
        float O  = sigmoidf_(gv[3] + bias.w);
        const int cidx = (mh * 256 + nt) * 128 + tid;
        float c = cws[cidx];
        c = F * c + In * G;
        cws[cidx] = c;
        float h = O * tanhf_(c);
        const int gb = mh * 32 + b_loc;
        out_t[(size_t)gb * H_ + j0 + u] = h;
        hxdst[gb * HX_ + j0 + u] = f2bf(h);
    } else if (tid < 192) {
        if (xnext) {
            const int e = (mh * 256 + nt) * 64 + (tid - 128);
            const int b = e >> 9, p = e & 511;
            hxdst[b * HX_ + H_ + p] = f2bf(xnext[e]);
        }
    }
}

// ================================ launcher ================================

extern "C" void kernel_launch(void* const* d_in, const int* in_sizes, int n_in,
                              void* d_out, int out_size, void* d_ws, size_t ws_size,
                              hipStream_t stream) {
    const float* x  = (const float*)d_in[0];
    const float* Wf = (const float*)d_in[1];
    const float* bf = (const float*)d_in[2];
    const float* Wi = (const float*)d_in[3];
    const float* bi = (const float*)d_in[4];
    const float* Wc = (const float*)d_in[5];
    const float* bc = (const float*)d_in[6];
    const float* Wo = (const float*)d_in[7];
    const float* bo = (const float*)d_in[8];
    float* out = (float*)d_out;

    // ws layout (bytes):
    //   Wp    : 4096*1536*2      = 12,582,912
    //   bp    : 4096*4           =     16,384
    //   bar   : 1024*4           =      4,096
    //   hx0/1 : 2*64*1536*2      =    393,216   (fallback)
    //   cws   : 512*128*4        =    262,144   (fallback)
    //   hxall : 513*64*1536*2    = 100,859,904  (persistent)  -> total ~114.1 MB
    char* wsb = (char*)d_ws;
    size_t off = 0;
    short*    Wp    = (short*)(wsb + off);    off += (size_t)NG * HX_ * 2;
    float*    bp    = (float*)(wsb + off);    off += (size_t)NG * 4;
    unsigned* bar   = (unsigned*)(wsb + off); off += (size_t)BAR_INTS * 4;
    short*    hx0   = (short*)(wsb + off);    off += (size_t)B_ * HX_ * 2;
    short*    hx1   = (short*)(wsb + off);    off += (size_t)B_ * HX_ * 2;
    float*    cws   = (float*)(wsb + off);    off += (size_t)512 * 128 * 4;
    short*    hxall = (short*)(wsb + off);
    const size_t need = off + (size_t)(T_ + 1) * B_ * HX_ * 2;

    pack_w<<<NG, 256, 0, stream>>>(Wf, Wi, Wc, Wo, bf, bi, bc, bo, Wp, bp);

    if (ws_size >= need) {
        const int nx4 = T_ * B_ * I_ / 4;
        init_hxall<<<(nx4 + B_ * H_ / 4 + 255) / 256, 256, 0, stream>>>(x, hxall, bar);
        lstm_all<<<dim3(NBLK), dim3(512), 0, stream>>>(Wp, bp, hxall, bar, out);
        return;
    }

    init_all<<<(B_ * HX_ + 512 * 128 + 255) / 256, 256, 0, stream>>>(x, hx0, cws);
    for (int t = 0; t < T_; ++t) {
        const short* hxsrc = (t & 1) ? hx1 : hx0;
        short*       hxdst = (t & 1) ? hx0 : hx1;
        const float* xnext = (t + 1 < T_) ? (x + (size_t)(t + 1) * B_ * I_) : nullptr;
        lstm_step<<<dim3(256, 2), 512, 0, stream>>>(
            Wp, bp, hxsrc, hxdst, xnext, cws,
            out + (size_t)t * B_ * H_);
    }
}